// Round 1
// baseline (295.882 us; speedup 1.0000x reference)
//
#include <hip/hip_runtime.h>
#include <math.h>

#define NB 16
#define NC 64
#define HW 160
#define PLANE (HW * HW)              // 25600
#define SG 161                        // site grid (H+1)
#define NSITES (NB * SG * SG)         // 414736
#define OUT_LD_OFF (NB * NC * PLANE)  // 26214400 (logdet output offset)

// Union shared memory:
//   det block (blockIdx 0): [A64: 4096][A32a: 1024][A32b: 1024][A16: 256][partial: 4]
//   conv blocks:            [W cache: 4096]
#define SMEM_FLOATS (4096 + 1024 + 1024 + 256 + 4)

// Map local submatrix index -> channel index for the INDS masks.
// n=64: identity. n=32: channels c%4 in {pa,pb}. n=16: c%4 == pa.
__device__ inline int chmap(int i, int n, int pa, int pb) {
    if (n == 64) return i;
    if (n == 32) return ((i >> 1) << 2) | ((i & 1) ? pb : pa);
    return (i << 2) | pa;
}

// One wave factorizes an n x n submatrix of W (LU, partial pivoting) in its
// private LDS region A (n*n floats) and returns log|det|. Wave-lockstep; the
// explicit s_waitcnt drains cross-lane LDS dependencies the compiler can't see.
__device__ float wave_lu_logabsdet(const float* __restrict__ W, float* A,
                                   int n, int sh, int pa, int pb, int lane) {
    for (int e = lane; e < n * n; e += 64) {
        int i = e >> sh, j = e & (n - 1);
        A[e] = W[chmap(i, n, pa, pb) * 64 + chmap(j, n, pa, pb)];
    }
    asm volatile("s_waitcnt lgkmcnt(0) vmcnt(0)" ::: "memory");
    float logdet = 0.f;
    for (int k = 0; k < n; ++k) {
        // --- pivot search over column k (rows >= k), 64-lane max+argmax ---
        float cand = -1.f;
        int idx = k;
        if (lane >= k && lane < n) {
            cand = fabsf(A[(lane << sh) + k]);
            idx = lane;
        }
        for (int off = 32; off; off >>= 1) {
            float oc = __shfl_down(cand, off, 64);
            int oi = __shfl_down(idx, off, 64);
            if (oc > cand) { cand = oc; idx = oi; }
        }
        int p = __shfl(idx, 0, 64);
        // --- swap rows k,p (lane = column) ---
        if (p != k && lane < n) {
            float tk = A[(k << sh) + lane];
            float tp = A[(p << sh) + lane];
            A[(k << sh) + lane] = tp;
            A[(p << sh) + lane] = tk;
        }
        asm volatile("s_waitcnt lgkmcnt(0)" ::: "memory");
        float piv = A[(k << sh) + k];  // broadcast read
        logdet += logf(fabsf(piv));
        float rpiv = 1.f / piv;
        float ckj = (lane < n) ? A[(k << sh) + lane] : 0.f;
        bool act = (lane > k) && (lane < n);
        for (int i2 = k + 1; i2 < n; ++i2) {
            float aik = A[(i2 << sh) + k];  // broadcast read (column k untouched below)
            float mult = aik * rpiv;
            if (act) A[(i2 << sh) + lane] = fmaf(-mult, ckj, A[(i2 << sh) + lane]);
        }
        asm volatile("s_waitcnt lgkmcnt(0)" ::: "memory");
    }
    return logdet;
}

__global__ __launch_bounds__(256, 4) void InvConv1x1GridAlign_kernel(
    const float* __restrict__ x, const float* __restrict__ ld_in,
    const float* __restrict__ W, float* __restrict__ out) {
    __shared__ __align__(16) float smem[SMEM_FLOATS];

    if (blockIdx.x == 0) {
        // ---- determinant block: 9 slogdets, one wave per matrix group ----
        float* A64 = smem;
        float* A32a = smem + 4096;
        float* A32b = smem + 5120;
        float* A16 = smem + 6144;
        float* partial = smem + 6400;
        int wid = threadIdx.x >> 6;
        int lane = threadIdx.x & 63;
        float part = 0.f;
        if (wid == 0) {
            part = 25281.f * wave_lu_logabsdet(W, A64, 64, 6, 0, 0, lane);  // middle: (159*159)
        } else if (wid == 1) {
            part  = wave_lu_logabsdet(W, A32a, 32, 5, 2, 3, lane);  // t: c%4 in {2,3}
            part += wave_lu_logabsdet(W, A32a, 32, 5, 0, 1, lane);  // b: {0,1}
            part *= 159.f;
        } else if (wid == 2) {
            part  = wave_lu_logabsdet(W, A32b, 32, 5, 1, 3, lane);  // l: {1,3}
            part += wave_lu_logabsdet(W, A32b, 32, 5, 0, 2, lane);  // r: {0,2}
            part *= 159.f;
        } else {
            part  = wave_lu_logabsdet(W, A16, 16, 4, 3, 0, lane);  // tl: {3}
            part += wave_lu_logabsdet(W, A16, 16, 4, 2, 0, lane);  // tr: {2}
            part += wave_lu_logabsdet(W, A16, 16, 4, 1, 0, lane);  // bl: {1}
            part += wave_lu_logabsdet(W, A16, 16, 4, 0, 0, lane);  // br: {0}
        }
        if (lane == 0) partial[wid] = part;
        __syncthreads();
        if (threadIdx.x < NB) {
            float dl = partial[0] + partial[1] + partial[2] + partial[3];
            out[OUT_LD_OFF + threadIdx.x] = ld_in[threadIdx.x] + dl;
        }
        return;
    }

    // ---- conv blocks: stage W (16 KB) into LDS once; broadcast ds_read in loop ----
    {
        float4* dst = (float4*)smem;
        const float4* src = (const float4*)W;
        for (int i = threadIdx.x; i < 1024; i += 256) dst[i] = src[i];
    }
    __syncthreads();

    // one thread per site (b, Y, X) on the 161x161 grid
    int s = (blockIdx.x - 1) * 256 + threadIdx.x;
    if (s >= NSITES) return;
    unsigned us = (unsigned)s;
    unsigned b = us / (SG * SG);
    unsigned rr = us - b * (SG * SG);
    unsigned uy = rr / SG;
    int Y = (int)uy;
    int X = (int)(rr - uy * SG);

    const float* xb = x + (size_t)b * NC * PLANE;
    float* ob = out + (size_t)b * NC * PLANE;

    // quadrant validity + in-plane pixel offsets (m = 2*ic + jc)
    bool okT = (Y >= 1), okB = (Y <= HW - 1), okL = (X >= 1), okR = (X <= HW - 1);
    bool v00 = okT && okL, v01 = okT && okR, v10 = okB && okL, v11 = okB && okR;
    int off00 = (Y - 1) * HW + (X - 1);
    int off01 = (Y - 1) * HW + X;
    int off10 = Y * HW + (X - 1);
    int off11 = Y * HW + X;

    float u[64];
#pragma unroll
    for (int o = 0; o < 64; ++o) u[o] = 0.f;

#pragma unroll 1  // keep body ~1K FMAs for I$; TLP hides chunk load latency
    for (int cc = 0; cc < 4; ++cc) {
        float v[16];
#pragma unroll
        for (int g4 = 0; g4 < 4; ++g4) {
            // Z-channel c = 4g+m reads input plane 4g+(3-m) (= c^3) at quadrant m
            const float* pg = xb + (size_t)(cc * 4 + g4) * 4 * PLANE;
            v[g4 * 4 + 0] = v00 ? pg[3 * PLANE + off00] : 0.f;
            v[g4 * 4 + 1] = v01 ? pg[2 * PLANE + off01] : 0.f;
            v[g4 * 4 + 2] = v10 ? pg[1 * PLANE + off10] : 0.f;
            v[g4 * 4 + 3] = v11 ? pg[0 * PLANE + off11] : 0.f;
        }
        const float* wc = smem + cc * 16;  // wave-uniform -> broadcast ds_read_b128
#pragma unroll
        for (int o = 0; o < 64; ++o) {
            const float4* wr = (const float4*)(wc + o * 64);
            float4 w0 = wr[0];
            float4 w1 = wr[1];
            float4 w2 = wr[2];
            float4 w3 = wr[3];
            float a = u[o];
            a = fmaf(w0.x, v[0], a);  a = fmaf(w0.y, v[1], a);
            a = fmaf(w0.z, v[2], a);  a = fmaf(w0.w, v[3], a);
            a = fmaf(w1.x, v[4], a);  a = fmaf(w1.y, v[5], a);
            a = fmaf(w1.z, v[6], a);  a = fmaf(w1.w, v[7], a);
            a = fmaf(w2.x, v[8], a);  a = fmaf(w2.y, v[9], a);
            a = fmaf(w2.z, v[10], a); a = fmaf(w2.w, v[11], a);
            a = fmaf(w3.x, v[12], a); a = fmaf(w3.y, v[13], a);
            a = fmaf(w3.z, v[14], a); a = fmaf(w3.w, v[15], a);
            u[o] = a;
        }
    }

    // scatter: u[o] -> output plane o^3, quadrant m = o&3 (same offsets as gather)
#pragma unroll
    for (int g = 0; g < 16; ++g) {
        float* pg = ob + (size_t)g * 4 * PLANE;
        if (v00) pg[3 * PLANE + off00] = u[g * 4 + 0];
        if (v01) pg[2 * PLANE + off01] = u[g * 4 + 1];
        if (v10) pg[1 * PLANE + off10] = u[g * 4 + 2];
        if (v11) pg[0 * PLANE + off11] = u[g * 4 + 3];
    }
}

extern "C" void kernel_launch(void* const* d_in, const int* in_sizes, int n_in,
                              void* d_out, int out_size, void* d_ws, size_t ws_size,
                              hipStream_t stream) {
    const float* x = (const float*)d_in[0];
    const float* ld = (const float*)d_in[1];
    const float* W = (const float*)d_in[2];
    float* out = (float*)d_out;
    int nconv = (NSITES + 255) / 256;  // 1621
    hipLaunchKernelGGL(InvConv1x1GridAlign_kernel, dim3(nconv + 1), dim3(256), 0,
                       stream, x, ld, W, out);
}

// Round 2
// 263.837 us; speedup vs baseline: 1.1215x; 1.1215x over previous
//
#include <hip/hip_runtime.h>
#include <math.h>

#define NB 16
#define NC 64
#define HW 160
#define PLANE (HW * HW)               // 25600
#define SG 161                        // site grid (H+1)
#define SGSQ (SG * SG)                // 25921
#define NSITES (NB * SGSQ)            // 414736
#define OUT_LD_OFF (NB * NC * PLANE)  // logdet output offset
#define TILE 256                      // sites per conv block
#define NCONV ((NSITES + TILE - 1) / TILE)  // 1621

// Union shared memory: det block uses first 6404 floats; conv blocks use
// vtile[32][256] = 8192 floats (32 KB). 4 blocks/CU at 128 KB LDS.
#define SMEM_FLOATS (32 * 256)

// Map local submatrix index -> channel index for the INDS masks.
__device__ inline int chmap(int i, int n, int pa, int pb) {
    if (n == 64) return i;
    if (n == 32) return ((i >> 1) << 2) | ((i & 1) ? pb : pa);
    return (i << 2) | pa;
}

// One wave factorizes an n x n submatrix of W (LU, partial pivoting) in its
// private LDS region A and returns log|det|. Wave-lockstep.
__device__ float wave_lu_logabsdet(const float* __restrict__ W, float* A,
                                   int n, int sh, int pa, int pb, int lane) {
    for (int e = lane; e < n * n; e += 64) {
        int i = e >> sh, j = e & (n - 1);
        A[e] = W[chmap(i, n, pa, pb) * 64 + chmap(j, n, pa, pb)];
    }
    asm volatile("s_waitcnt lgkmcnt(0) vmcnt(0)" ::: "memory");
    float logdet = 0.f;
    for (int k = 0; k < n; ++k) {
        float cand = -1.f;
        int idx = k;
        if (lane >= k && lane < n) {
            cand = fabsf(A[(lane << sh) + k]);
            idx = lane;
        }
        for (int off = 32; off; off >>= 1) {
            float oc = __shfl_down(cand, off, 64);
            int oi = __shfl_down(idx, off, 64);
            if (oc > cand) { cand = oc; idx = oi; }
        }
        int p = __shfl(idx, 0, 64);
        if (p != k && lane < n) {
            float tk = A[(k << sh) + lane];
            float tp = A[(p << sh) + lane];
            A[(k << sh) + lane] = tp;
            A[(p << sh) + lane] = tk;
        }
        asm volatile("s_waitcnt lgkmcnt(0)" ::: "memory");
        float piv = A[(k << sh) + k];
        logdet += logf(fabsf(piv));
        float rpiv = 1.f / piv;
        float ckj = (lane < n) ? A[(k << sh) + lane] : 0.f;
        bool act = (lane > k) && (lane < n);
        for (int i2 = k + 1; i2 < n; ++i2) {
            float aik = A[(i2 << sh) + k];
            float mult = aik * rpiv;
            if (act) A[(i2 << sh) + lane] = fmaf(-mult, ckj, A[(i2 << sh) + lane]);
        }
        asm volatile("s_waitcnt lgkmcnt(0)" ::: "memory");
    }
    return logdet;
}

__global__ __launch_bounds__(256, 4) void InvConv1x1GridAlign_kernel(
    const float* __restrict__ x, const float* __restrict__ ld_in,
    const float* __restrict__ W, float* __restrict__ out) {
    __shared__ __align__(16) float smem[SMEM_FLOATS];
    const int tid = threadIdx.x;

    if (blockIdx.x == 0) {
        // ---- determinant block: 9 slogdets, one wave per matrix group ----
        float* A64 = smem;
        float* A32a = smem + 4096;
        float* A32b = smem + 5120;
        float* A16 = smem + 6144;
        float* partial = smem + 6400;
        int wid = tid >> 6;
        int lane = tid & 63;
        float part = 0.f;
        if (wid == 0) {
            part = 25281.f * wave_lu_logabsdet(W, A64, 64, 6, 0, 0, lane);
        } else if (wid == 1) {
            part  = wave_lu_logabsdet(W, A32a, 32, 5, 2, 3, lane);
            part += wave_lu_logabsdet(W, A32a, 32, 5, 0, 1, lane);
            part *= 159.f;
        } else if (wid == 2) {
            part  = wave_lu_logabsdet(W, A32b, 32, 5, 1, 3, lane);
            part += wave_lu_logabsdet(W, A32b, 32, 5, 0, 2, lane);
            part *= 159.f;
        } else {
            part  = wave_lu_logabsdet(W, A16, 16, 4, 3, 0, lane);
            part += wave_lu_logabsdet(W, A16, 16, 4, 2, 0, lane);
            part += wave_lu_logabsdet(W, A16, 16, 4, 1, 0, lane);
            part += wave_lu_logabsdet(W, A16, 16, 4, 0, 0, lane);
        }
        if (lane == 0) partial[wid] = part;
        __syncthreads();
        if (tid < NB) {
            float dl = partial[0] + partial[1] + partial[2] + partial[3];
            out[OUT_LD_OFF + tid] = ld_in[tid] + dl;
        }
        return;
    }

    // ---- conv blocks: GEMM tile, 64 outputs x 256 sites per block ----
    // u[o][s] = sum_k W[o][k] * v[k][s]; v[k][s] = x[b][k^3][Y-1+dy][X-1+dx]
    // (dy=(k>>1)&1, dx=k&1), zero outside. Output u[o][s] -> out[b][o^3][quad].
    const int tile0 = ((int)blockIdx.x - 1) * TILE;
    const int lane = tid & 63;
    const int wid = tid >> 6;
    // wave-uniform output base -> W reads become s_load from K$
    const int wo = __builtin_amdgcn_readfirstlane(wid << 4);

    float acc[16][4];
#pragma unroll
    for (int j = 0; j < 16; ++j)
#pragma unroll
        for (int s2 = 0; s2 < 4; ++s2) acc[j][s2] = 0.f;

    for (int half = 0; half < 2; ++half) {
        __syncthreads();  // previous compute done before restaging
        // ---- stage vtile[krow][s], krow = k - 32*half, 256 sites ----
        {
            const int scol = (tid & 31) << 3;  // 8 consecutive sites per thread
#pragma unroll
            for (int p = 0; p < 4; ++p) {
                const int krow = (tid >> 5) + (p << 3);  // 0..31
                const int k = (half << 5) + krow;
                const int pl = k ^ 3;
                const int dy = (k >> 1) & 1, dx = k & 1;
                // decode first site, then increment with wrap (<=1 wrap per 8)
                const int s0 = tile0 + scol;
                unsigned us = (unsigned)s0;
                unsigned b0 = us / SGSQ;
                unsigned rr = us - b0 * SGSQ;
                unsigned Y0 = rr / SG;
                unsigned X0 = rr - Y0 * SG;
                float vals[8];
#pragma unroll
                for (int j = 0; j < 8; ++j) {
                    unsigned X = X0 + j, Y = Y0, b = b0;
                    if (X >= SG) { X -= SG; ++Y; if (Y >= SG) { Y = 0; ++b; } }
                    float vv = 0.f;
                    int py = (int)Y - 1 + dy;
                    int px = (int)X - 1 + dx;
                    if ((s0 + j) < NSITES && (unsigned)py < HW && (unsigned)px < HW)
                        vv = x[(size_t)b * (NC * PLANE) + (size_t)pl * PLANE +
                               (unsigned)(py * HW + px)];
                    vals[j] = vv;
                }
                float* dst = &smem[krow * 256 + scol];
                *(float4*)(dst) = make_float4(vals[0], vals[1], vals[2], vals[3]);
                *(float4*)(dst + 4) = make_float4(vals[4], vals[5], vals[6], vals[7]);
            }
        }
        __syncthreads();
        // ---- compute 32 k-steps: per k, 16 scalar W + 1 ds_read_b128 + 64 FMA ----
        const float* vrow = smem + (lane << 2);
#pragma unroll 4
        for (int kk = 0; kk < 32; ++kk) {
            const int k = (half << 5) + kk;
            float w[16];
#pragma unroll
            for (int j = 0; j < 16; ++j) w[j] = W[(wo + j) * 64 + k];  // s_load
            const float4 v4 = *(const float4*)(vrow + (kk << 8));
#pragma unroll
            for (int j = 0; j < 16; ++j) {
                acc[j][0] = fmaf(w[j], v4.x, acc[j][0]);
                acc[j][1] = fmaf(w[j], v4.y, acc[j][1]);
                acc[j][2] = fmaf(w[j], v4.z, acc[j][2]);
                acc[j][3] = fmaf(w[j], v4.w, acc[j][3]);
            }
        }
    }

    // ---- epilogue: scatter acc[j][s] -> out[b][(wo+j)^3][quad pixel] ----
    const int sbase = tile0 + (lane << 2);
    unsigned Ys[4], Xs[4];
    size_t obase[4];
    bool okv[4];
    {
        unsigned us = (unsigned)sbase;
        unsigned b0 = us / SGSQ;
        unsigned rr = us - b0 * SGSQ;
        unsigned Y0 = rr / SG;
        unsigned X0 = rr - Y0 * SG;
#pragma unroll
        for (int s2 = 0; s2 < 4; ++s2) {
            unsigned X = X0 + s2, Y = Y0, b = b0;
            if (X >= SG) { X -= SG; ++Y; if (Y >= SG) { Y = 0; ++b; } }
            Ys[s2] = Y;
            Xs[s2] = X;
            obase[s2] = (size_t)b * (NC * PLANE);
            okv[s2] = (sbase + s2) < NSITES;
        }
    }
#pragma unroll
    for (int j = 0; j < 16; ++j) {
        const int o = wo + j;
        const int pl = o ^ 3;
        const int dy = (o >> 1) & 1, dx = o & 1;
#pragma unroll
        for (int s2 = 0; s2 < 4; ++s2) {
            int py = (int)Ys[s2] - 1 + dy;
            int px = (int)Xs[s2] - 1 + dx;
            if (okv[s2] && (unsigned)py < HW && (unsigned)px < HW)
                out[obase[s2] + (size_t)pl * PLANE + (unsigned)(py * HW + px)] =
                    acc[j][s2];
        }
    }
}

extern "C" void kernel_launch(void* const* d_in, const int* in_sizes, int n_in,
                              void* d_out, int out_size, void* d_ws, size_t ws_size,
                              hipStream_t stream) {
    const float* x = (const float*)d_in[0];
    const float* ld = (const float*)d_in[1];
    const float* W = (const float*)d_in[2];
    float* out = (float*)d_out;
    hipLaunchKernelGGL(InvConv1x1GridAlign_kernel, dim3(NCONV + 1), dim3(256), 0,
                       stream, x, ld, W, out);
}

// Round 4
// 262.534 us; speedup vs baseline: 1.1270x; 1.0050x over previous
//
#include <hip/hip_runtime.h>
#include <math.h>

#define NB 16
#define NC 64
#define HW 160
#define PLANE (HW * HW)               // 25600
#define SG 161                        // site grid (H+1)
#define SGSQ (SG * SG)                // 25921
#define NSITES (NB * SGSQ)            // 414736
#define OUT_LD_OFF (NB * NC * PLANE)  // logdet output offset
#define TILE 256                      // sites per conv block
#define NCONV ((NSITES + TILE - 1) / TILE)  // 1621

// Union shared memory: det block uses first 6404 floats; conv blocks use
// vtile[32 krows][256 sites] = 8192 floats (32 KB). 4 blocks/CU.
#define SMEM_FLOATS (32 * 256)

// Map local submatrix index -> channel index for the INDS masks.
__device__ inline int chmap(int i, int n, int pa, int pb) {
    if (n == 64) return i;
    if (n == 32) return ((i >> 1) << 2) | ((i & 1) ? pb : pa);
    return (i << 2) | pa;
}

// One wave factorizes an n x n submatrix of W (LU, partial pivoting) in its
// private LDS region A and returns log|det|. Wave-lockstep.
__device__ float wave_lu_logabsdet(const float* __restrict__ W, float* A,
                                   int n, int sh, int pa, int pb, int lane) {
    for (int e = lane; e < n * n; e += 64) {
        int i = e >> sh, j = e & (n - 1);
        A[e] = W[chmap(i, n, pa, pb) * 64 + chmap(j, n, pa, pb)];
    }
    asm volatile("s_waitcnt lgkmcnt(0) vmcnt(0)" ::: "memory");
    float logdet = 0.f;
    for (int k = 0; k < n; ++k) {
        float cand = -1.f;
        int idx = k;
        if (lane >= k && lane < n) {
            cand = fabsf(A[(lane << sh) + k]);
            idx = lane;
        }
        for (int off = 32; off; off >>= 1) {
            float oc = __shfl_down(cand, off, 64);
            int oi = __shfl_down(idx, off, 64);
            if (oc > cand) { cand = oc; idx = oi; }
        }
        int p = __shfl(idx, 0, 64);
        if (p != k && lane < n) {
            float tk = A[(k << sh) + lane];
            float tp = A[(p << sh) + lane];
            A[(k << sh) + lane] = tp;
            A[(p << sh) + lane] = tk;
        }
        asm volatile("s_waitcnt lgkmcnt(0)" ::: "memory");
        float piv = A[(k << sh) + k];
        logdet += logf(fabsf(piv));
        float rpiv = 1.f / piv;
        float ckj = (lane < n) ? A[(k << sh) + lane] : 0.f;
        bool act = (lane > k) && (lane < n);
        for (int i2 = k + 1; i2 < n; ++i2) {
            float aik = A[(i2 << sh) + k];
            float mult = aik * rpiv;
            if (act) A[(i2 << sh) + lane] = fmaf(-mult, ckj, A[(i2 << sh) + lane]);
        }
        asm volatile("s_waitcnt lgkmcnt(0)" ::: "memory");
    }
    return logdet;
}

__global__ __launch_bounds__(256, 4) void InvConv1x1GridAlign_kernel(
    const float* __restrict__ x, const float* __restrict__ ld_in,
    const float* __restrict__ W, float* __restrict__ out) {
    __shared__ __align__(16) float smem[SMEM_FLOATS];
    const int tid = threadIdx.x;

    if (blockIdx.x == 0) {
        // ---- determinant block: 9 slogdets, one wave per matrix group ----
        float* A64 = smem;
        float* A32a = smem + 4096;
        float* A32b = smem + 5120;
        float* A16 = smem + 6144;
        float* partial = smem + 6400;
        int wid = tid >> 6;
        int lane = tid & 63;
        float part = 0.f;
        if (wid == 0) {
            part = 25281.f * wave_lu_logabsdet(W, A64, 64, 6, 0, 0, lane);
        } else if (wid == 1) {
            part  = wave_lu_logabsdet(W, A32a, 32, 5, 2, 3, lane);
            part += wave_lu_logabsdet(W, A32a, 32, 5, 0, 1, lane);
            part *= 159.f;
        } else if (wid == 2) {
            part  = wave_lu_logabsdet(W, A32b, 32, 5, 1, 3, lane);
            part += wave_lu_logabsdet(W, A32b, 32, 5, 0, 2, lane);
            part *= 159.f;
        } else {
            part  = wave_lu_logabsdet(W, A16, 16, 4, 3, 0, lane);
            part += wave_lu_logabsdet(W, A16, 16, 4, 2, 0, lane);
            part += wave_lu_logabsdet(W, A16, 16, 4, 1, 0, lane);
            part += wave_lu_logabsdet(W, A16, 16, 4, 0, 0, lane);
        }
        if (lane == 0) partial[wid] = part;
        __syncthreads();
        if (tid < NB) {
            float dl = partial[0] + partial[1] + partial[2] + partial[3];
            out[OUT_LD_OFF + tid] = ld_in[tid] + dl;
        }
        return;
    }

    // ---- conv blocks: GEMM tile, 64 outputs x 256 sites ----
    // u[o][s] = sum_k W[o][k] * v[k][s]; v[k][s] = x[b][k^3][Y-1+dy][X-1+dx]
    // (dy=(k>>1)&1, dx=k&1; offsets repeat mod 4). Lane owns sites
    // {lane, lane+64, lane+128, lane+192}: every global/LDS access is
    // lane-stride-1 -> coalesced loads/stores, conflict-free LDS.
    const int tile0 = ((int)blockIdx.x - 1) * TILE;
    const int lane = tid & 63;
    const int wid = tid >> 6;
    const int wo = __builtin_amdgcn_readfirstlane(wid << 4);  // wave-uniform

    // per-thread staging site decode (site = tile0 + tid)
    const int offm[4] = {0, 1, HW, HW + 1};
    bool vm[4];
    int baseoff;
    const float* xb;
    {
        int s = tile0 + tid;
        bool sok = s < NSITES;
        unsigned us = (unsigned)(sok ? s : 0);
        unsigned b = us / SGSQ;
        unsigned rr = us - b * SGSQ;
        unsigned Y = rr / SG;
        unsigned X = rr - Y * SG;
        xb = x + (size_t)b * (NC * PLANE);
        baseoff = ((int)Y - 1) * HW + ((int)X - 1);
        bool okT = sok && (Y >= 1), okB = sok && (Y <= HW - 1);
        bool okL = (X >= 1), okR = (X <= HW - 1);
        vm[0] = okT && okL; vm[1] = okT && okR;
        vm[2] = okB && okL; vm[3] = okB && okR;
    }

    float acc[16][4];
#pragma unroll
    for (int j = 0; j < 16; ++j)
#pragma unroll
        for (int s2 = 0; s2 < 4; ++s2) acc[j][s2] = 0.f;

#pragma unroll 1
    for (int half = 0; half < 2; ++half) {
        __syncthreads();  // previous compute done before restaging
        // ---- stage vtile[krow][tid]: 1 coalesced cond. load + 1 ds_write ----
#pragma unroll 8
        for (int krow = 0; krow < 32; ++krow) {
            const int k = (half << 5) + krow;
            const int pl = k ^ 3;
            const int m = krow & 3;  // k mod 4 (32 = 0 mod 4)
            float val = vm[m] ? xb[pl * PLANE + baseoff + offm[m]] : 0.f;
            smem[(krow << 8) + tid] = val;
        }
        __syncthreads();
        // ---- compute: per kb (4 k-steps), 16 ds_read_b32 + wave-uniform W ----
#pragma unroll 1
        for (int kb = 0; kb < 8; ++kb) {
            float v[4][4];
            const float* vb = smem + (kb << 10) + lane;
#pragma unroll
            for (int kk = 0; kk < 4; ++kk)
#pragma unroll
                for (int s2 = 0; s2 < 4; ++s2)
                    v[kk][s2] = vb[(kk << 8) + (s2 << 6)];
            const int k0 = (half << 5) + (kb << 2);
#pragma unroll
            for (int jb = 0; jb < 2; ++jb) {
                float4 w4[8];  // wave-uniform -> s_load_dwordx4 from K$
#pragma unroll
                for (int j = 0; j < 8; ++j)
                    w4[j] = *(const float4*)(W + (wo + (jb << 3) + j) * 64 + k0);
#pragma unroll
                for (int j = 0; j < 8; ++j) {
                    const int jj = (jb << 3) + j;
#pragma unroll
                    for (int kk = 0; kk < 4; ++kk) {
                        const float wjk = (kk == 0) ? w4[j].x
                                        : (kk == 1) ? w4[j].y
                                        : (kk == 2) ? w4[j].z : w4[j].w;
#pragma unroll
                        for (int s2 = 0; s2 < 4; ++s2)
                            acc[jj][s2] = fmaf(wjk, v[kk][s2], acc[jj][s2]);
                    }
                }
            }
        }
    }

    // ---- epilogue: lane's 4 sites are stride-64 -> coalesced stores ----
#pragma unroll
    for (int s2 = 0; s2 < 4; ++s2) {
        int s = tile0 + lane + (s2 << 6);
        bool sok = s < NSITES;
        unsigned us = (unsigned)(sok ? s : 0);
        unsigned b = us / SGSQ;
        unsigned rr = us - b * SGSQ;
        unsigned Y = rr / SG;
        unsigned X = rr - Y * SG;
        float* ob = out + (size_t)b * (NC * PLANE);
        int boff = ((int)Y - 1) * HW + ((int)X - 1);
        bool okT = sok && (Y >= 1), okB = sok && (Y <= HW - 1);
        bool okL = (X >= 1), okR = (X <= HW - 1);
        bool wm[4] = {okT && okL, okT && okR, okB && okL, okB && okR};
#pragma unroll
        for (int j = 0; j < 16; ++j) {
            const int o = wo + j;
            const int pl = o ^ 3;
            const int m = j & 3;  // o mod 4 (wo multiple of 16)
            if (wm[m]) ob[pl * PLANE + boff + offm[m]] = acc[j][s2];
        }
    }
}

extern "C" void kernel_launch(void* const* d_in, const int* in_sizes, int n_in,
                              void* d_out, int out_size, void* d_ws, size_t ws_size,
                              hipStream_t stream) {
    const float* x = (const float*)d_in[0];
    const float* ld = (const float*)d_in[1];
    const float* W = (const float*)d_in[2];
    float* out = (float*)d_out;
    hipLaunchKernelGGL(InvConv1x1GridAlign_kernel, dim3(NCONV + 1), dim3(256), 0,
                       stream, x, ld, W, out);
}